// Round 9
// baseline (452.212 us; speedup 1.0000x reference)
//
#include <hip/hip_runtime.h>
#include <hip/hip_bf16.h>
#include <math.h>

// SparseBEVSelfAttention fused pipeline, fp32.
// B=1, Q=4096, C=256, H=8, D=32.
//
// Pipeline:
//  prep     : tau[q][h] = q . W_tau[h] + b_tau[h]; centers from query_pos
//  dminmax  : read mask once (auto-detect int32 vs 1-byte bool layout)
//             -> 2MB bitmask; per-q dmin/dmax over unmasked k
//             -> analytic softmax max m[q][h] = -dsel*tau
//  ln(v) -> gemm W_v -> vp
//  pv       : per (q-tile 256, head, k-split 1024): p = exp(s - m) built in
//             LDS (transposed), 8x4 register-tiled PV GEMM, row-sum l
//             partials; V tile register-prefetched
//  lcomb    : rl = 1/sum(l partials)
//  gemm proj: NSUM=4 split reduce, A scaled by rl (per q,h) during staging
//  ln -> gemm m1 (exact gelu) -> gemm m2 -> ln(residual) -> out
//
// R7 fix: mb_b (mask bitmask) is 4096 x 64 u64 = 2MB = 524288 floats; the
// previous layout reserved 131072 floats, so ln(v) clobbered mask rows
// q >= 1024 (deterministic absmax 6.89 in R6/R7). Buffers shifted.

#define Qn 4096
#define Cn 256
#define Hn 8
#define Dn 32

__device__ __forceinline__ float gelu_exact(float x) {
    return 0.5f * x * (1.0f + erff(x * 0.70710678118654752f));
}

// Hot-path distance. dminmax and pv use the identical instruction sequence
// so d (hence s) matches bitwise between m-computation and p-computation.
__device__ __forceinline__ float fast_dist(float2 cq, float2 ck) {
    float dx = cq.x - ck.x, dy = cq.y - ck.y;
    return __builtin_amdgcn_sqrtf(fmaf(dx, dx, dy * dy));
}

// ---------------------------------------------------------------------------
// K1: tau[q][h] = q_row . W_tau[h] + b_tau[h];  centers[q] = affine(query_pos)
__global__ __launch_bounds__(256) void prep_kernel(const float* __restrict__ qpos,
                                                   const float* __restrict__ q,
                                                   const float* __restrict__ W_tau,
                                                   const float* __restrict__ b_tau,
                                                   float* __restrict__ tau,
                                                   float* __restrict__ centers) {
    int idx = blockIdx.x * 256 + threadIdx.x;   // 32768 threads
    int qi = idx >> 3, h = idx & 7;
    const float4* qr = (const float4*)(q + (size_t)qi * Cn);
    const float4* wr = (const float4*)(W_tau + (size_t)h * Cn);
    float s = 0.f;
#pragma unroll 8
    for (int c = 0; c < Cn / 4; ++c) {
        float4 a = qr[c], b = wr[c];
        s = fmaf(a.x, b.x, s); s = fmaf(a.y, b.y, s);
        s = fmaf(a.z, b.z, s); s = fmaf(a.w, b.w, s);
    }
    tau[idx] = s + b_tau[h];
    if (h == 0) {
        float px = qpos[qi * 2], py = qpos[qi * 2 + 1];
        centers[qi * 2]     = px * 102.4f - 51.2f;
        centers[qi * 2 + 1] = py * 102.4f - 51.2f;
    }
}

// ---------------------------------------------------------------------------
// K2: one wave per q row. Reads the mask once, writes 64-bit ballot bitmask
// (2MB), computes dmin/dmax over unmasked k, emits m[q][h] = -dsel * tau
// (analytic softmax max; monotone rounding).
//
// Mask ABI probe: int32 0/1 words have bytes 1..3 zero; random 0/1 bytes
// don't. Wave-uniform branch; P(miss) ~ 8^-64.
__global__ __launch_bounds__(256) void dminmax_kernel(const void* __restrict__ maskp,
                                                      const float* __restrict__ centers,
                                                      const float* __restrict__ tau,
                                                      unsigned long long* __restrict__ mbits,
                                                      float* __restrict__ mfin) {
    int wave = threadIdx.x >> 6, lane = threadIdx.x & 63;
    int q = blockIdx.x * 4 + wave;
    const unsigned* mw = (const unsigned*)maskp;
    bool u8 = (__ballot((mw[lane] & 0xFFFFFF00u) != 0) != 0ULL);
    const float2* c2 = (const float2*)centers;
    float2 cq = c2[q];
    const int* mrow32 = (const int*)maskp + (size_t)q * Qn;
    const unsigned char* mrow8 = (const unsigned char*)maskp + (size_t)q * Qn;
    unsigned long long* orow = mbits + (size_t)q * (Qn / 64);
    float dmin = 3.0e38f, dmax = -3.0e38f;
    for (int k0 = 0; k0 < Qn; k0 += 64) {
        int k = k0 + lane;
        int mk = u8 ? (int)mrow8[k] : mrow32[k];
        float d = fast_dist(cq, c2[k]);
        unsigned long long bal = __ballot(mk != 0);
        if (lane == 0) orow[k0 >> 6] = bal;
        if (!mk) { dmin = fminf(dmin, d); dmax = fmaxf(dmax, d); }
    }
#pragma unroll
    for (int off = 1; off < 64; off <<= 1) {
        dmin = fminf(dmin, __shfl_xor(dmin, off));
        dmax = fmaxf(dmax, __shfl_xor(dmax, off));
    }
    if (lane < Hn) {
        float tq = tau[q * Hn + lane];
        float dsel = (tq >= 0.f) ? dmin : dmax;
        mfin[q * Hn + lane] = -dsel * tq;
    }
}

// ---------------------------------------------------------------------------
// LayerNorm over last dim (256). One wave per row. Optional residual X2.
__global__ __launch_bounds__(64) void ln_kernel(const float* __restrict__ X,
                                                const float* __restrict__ X2,
                                                const float* __restrict__ g,
                                                const float* __restrict__ b,
                                                float* __restrict__ out) {
    int row = blockIdx.x;
    int t = threadIdx.x;
    float4 x = ((const float4*)(X + (size_t)row * Cn))[t];
    if (X2) {
        float4 y = ((const float4*)(X2 + (size_t)row * Cn))[t];
        x.x += y.x; x.y += y.y; x.z += y.z; x.w += y.w;
    }
    float s  = x.x + x.y + x.z + x.w;
    float ss = fmaf(x.x, x.x, fmaf(x.y, x.y, fmaf(x.z, x.z, x.w * x.w)));
#pragma unroll
    for (int off = 1; off < 64; off <<= 1) {
        s  += __shfl_xor(s, off);
        ss += __shfl_xor(ss, off);
    }
    float mean = s * (1.0f / Cn);
    float var  = ss * (1.0f / Cn) - mean * mean;
    float inv  = rsqrtf(var + 1e-5f);
    float4 gg = ((const float4*)g)[t];
    float4 bb = ((const float4*)b)[t];
    float4 o;
    o.x = fmaf((x.x - mean) * inv, gg.x, bb.x);
    o.y = fmaf((x.y - mean) * inv, gg.y, bb.y);
    o.z = fmaf((x.z - mean) * inv, gg.z, bb.z);
    o.w = fmaf((x.w - mean) * inv, gg.w, bb.w);
    ((float4*)(out + (size_t)row * Cn))[t] = o;
}

// ---------------------------------------------------------------------------
// Generic fp32 GEMM: C[M][N] = act( scale_row(sum_s A_s[M][K]) @ W[N][K]^T + bias ).
// 64x64 tile, BK=32, 256 threads, 4x4 acc per thread. XOR-swizzled,
// DOUBLE-BUFFERED LDS: one barrier per K-tile; stage(t+1) issued before
// compute(t) so global-load latency hides under the FMA phase.
// SCALE: multiply A element [r][c] by ascale[r*Hn + (c>>5)] after split-sum.
template <int ACT, int NSUM, int SCALE>
__global__ __launch_bounds__(256) void gemm_kernel(const float* __restrict__ A,
                                                   const float* __restrict__ W,
                                                   const float* __restrict__ bias,
                                                   const float* __restrict__ ascale,
                                                   float* __restrict__ Cout,
                                                   int M, int N, int K) {
    __shared__ float As[2][64][32];
    __shared__ float Ws[2][64][32];
    const int tid = threadIdx.x;
    const int row0 = blockIdx.x * 64;
    const int col0 = blockIdx.y * 64;
    const int tx = tid & 15;            // n-group 0..15
    const int ty = tid >> 4;            // m-group 0..15
    const int m0 = ty * 4, n0 = tx * 4;
    const int sr = tid >> 3;            // staging row 0..31
    const int sc4 = tid & 7;            // staging float4-col 0..7
    const size_t sumstride = (size_t)M * K;
    float acc[4][4] = {};

    auto stage = [&](int buf, int kb) {
#pragma unroll
        for (int half = 0; half < 2; ++half) {
            int r = sr + half * 32;
            float4 av = *(const float4*)(A + (size_t)(row0 + r) * K + kb + sc4 * 4);
#pragma unroll
            for (int s2 = 1; s2 < NSUM; ++s2) {
                float4 a2 = *(const float4*)(A + s2 * sumstride + (size_t)(row0 + r) * K + kb + sc4 * 4);
                av.x += a2.x; av.y += a2.y; av.z += a2.z; av.w += a2.w;
            }
            if (SCALE) {
                float sc = ascale[(size_t)(row0 + r) * Hn + ((kb + sc4 * 4) >> 5)];
                av.x *= sc; av.y *= sc; av.z *= sc; av.w *= sc;
            }
            int cs = sc4 ^ ((r >> 2) & 7);
            *(float4*)&As[buf][r][cs * 4] = av;
            float4 wv = *(const float4*)(W + (size_t)(col0 + r) * K + kb + sc4 * 4);
            *(float4*)&Ws[buf][r][cs * 4] = wv;
        }
    };

    const int NT = K / 32;
    stage(0, 0);
    __syncthreads();
    for (int kt = 0; kt < NT; ++kt) {
        int cur = kt & 1;
        if (kt + 1 < NT) stage(cur ^ 1, (kt + 1) * 32);
#pragma unroll
        for (int c4 = 0; c4 < 8; ++c4) {
            float4 a4[4], w4[4];
#pragma unroll
            for (int i = 0; i < 4; ++i)
                a4[i] = *(const float4*)&As[cur][m0 + i][((c4 ^ (ty & 7)) * 4)];
#pragma unroll
            for (int j = 0; j < 4; ++j)
                w4[j] = *(const float4*)&Ws[cur][n0 + j][((c4 ^ (tx & 7)) * 4)];
            float aa[4][4], ww[4][4];
#pragma unroll
            for (int i = 0; i < 4; ++i) {
                aa[i][0] = a4[i].x; aa[i][1] = a4[i].y; aa[i][2] = a4[i].z; aa[i][3] = a4[i].w;
                ww[i][0] = w4[i].x; ww[i][1] = w4[i].y; ww[i][2] = w4[i].z; ww[i][3] = w4[i].w;
            }
#pragma unroll
            for (int i = 0; i < 4; ++i)
#pragma unroll
                for (int j = 0; j < 4; ++j) {
                    acc[i][j] = fmaf(aa[i][0], ww[j][0], acc[i][j]);
                    acc[i][j] = fmaf(aa[i][1], ww[j][1], acc[i][j]);
                    acc[i][j] = fmaf(aa[i][2], ww[j][2], acc[i][j]);
                    acc[i][j] = fmaf(aa[i][3], ww[j][3], acc[i][j]);
                }
        }
        __syncthreads();
    }
#pragma unroll
    for (int i = 0; i < 4; ++i) {
        float4 o;
        float* oc = &o.x;
#pragma unroll
        for (int j = 0; j < 4; ++j) {
            float val = acc[i][j] + bias[col0 + n0 + j];
            if (ACT == 1) val = gelu_exact(val);
            oc[j] = val;
        }
        *(float4*)(Cout + (size_t)(row0 + m0 + i) * N + col0 + n0) = o;
    }
}

// ---------------------------------------------------------------------------
// K3: PV. Block = (q-tile 256, head, k-split of 1024). P (unnormalized,
// exp(s-m)) built into LDS transposed [k][q]; 8x4 register-tiled GEMM vs
// V-tile; per-row l partial accumulated as by-product. V/center tile for
// k-tile t+1 register-prefetched during P-gen/GEMM of tile t. grid (16,8,4).
__global__ __launch_bounds__(256) void pv_kernel(const float* __restrict__ centers,
                                                 const float* __restrict__ tau,
                                                 const unsigned* __restrict__ mbits,
                                                 const float* __restrict__ vp,
                                                 const float* __restrict__ mfin,
                                                 float* __restrict__ apart,
                                                 float* __restrict__ lpart) {
    __shared__ float vt[32][36];    // V tile [k][d], conflict-free
    __shared__ float pt[32][260];   // P tile [k][q], conflict-free
    __shared__ float2 ct[32];
    int q0 = blockIdx.x * 256;
    int h = blockIdx.y;
    int split = blockIdx.z;
    int t = threadIdx.x;

    // P-generation role: this thread owns one q row, all 32 kk per tile
    int qp = q0 + t;
    const float2* c2 = (const float2*)centers;
    float2 cq = c2[qp];
    float tq = tau[qp * Hn + h];
    float mq = mfin[qp * Hn + h];
    const unsigned* mrow = mbits + (size_t)qp * (Qn / 32);
    float lacc0 = 0.f, lacc1 = 0.f;

    // GEMM role: 8q x 4d accumulator
    int tx = t & 7, ty = t >> 3;    // d0 = tx*4, q rows ty*8..ty*8+7
    float acc[8][4] = {};

    // staging role
    int kk_ = t >> 3, c4_ = t & 7;

    int kbeg = split * 1024, kend = kbeg + 1024;
    // prefetch first tile into regs
    float4 vreg = *(const float4*)(vp + (size_t)(kbeg + kk_) * Cn + h * Dn + c4_ * 4);
    float2 creg = (t < 32) ? c2[kbeg + t] : make_float2(0.f, 0.f);

    for (int kb = kbeg; kb < kend; kb += 32) {
        unsigned w = mrow[kb >> 5];           // L2-resident, issued early
        __syncthreads();            // previous tile fully consumed
        *(float4*)&vt[kk_][c4_ * 4] = vreg;
        if (t < 32) ct[t] = creg;
        // prefetch next tile (dummy = kbeg on last iter; values unused)
        int nkb = (kb + 32 < kend) ? kb + 32 : kbeg;
        vreg = *(const float4*)(vp + (size_t)(nkb + kk_) * Cn + h * Dn + c4_ * 4);
        if (t < 32) creg = c2[nkb + t];
        __syncthreads();
#pragma unroll
        for (int kk = 0; kk < 32; kk += 2) {
            float s0 = -fast_dist(cq, ct[kk]) * tq;
            float s1 = -fast_dist(cq, ct[kk + 1]) * tq;
            float e0 = __expf(fminf(s0 - mq, 0.f));
            float e1 = __expf(fminf(s1 - mq, 0.f));
            float p0 = ((w >> kk) & 1u) ? 0.f : e0;
            float p1 = ((w >> (kk + 1)) & 1u) ? 0.f : e1;
            lacc0 += p0; lacc1 += p1;
            pt[kk][t] = p0;
            pt[kk + 1][t] = p1;
        }
        __syncthreads();
#pragma unroll
        for (int kk = 0; kk < 32; ++kk) {
            float4 v4 = *(const float4*)&vt[kk][tx * 4];
            float4 p0 = *(const float4*)&pt[kk][ty * 8];
            float4 p1 = *(const float4*)&pt[kk][ty * 8 + 4];
            float va[4] = {v4.x, v4.y, v4.z, v4.w};
            float pa[8] = {p0.x, p0.y, p0.z, p0.w, p1.x, p1.y, p1.z, p1.w};
#pragma unroll
            for (int i = 0; i < 8; ++i)
#pragma unroll
                for (int j = 0; j < 4; ++j)
                    acc[i][j] = fmaf(pa[i], va[j], acc[i][j]);
        }
    }
    float* dst = apart + (size_t)split * (Qn * Cn);
#pragma unroll
    for (int i = 0; i < 8; ++i) {
        float4 o = make_float4(acc[i][0], acc[i][1], acc[i][2], acc[i][3]);
        *(float4*)(dst + (size_t)(q0 + ty * 8 + i) * Cn + h * Dn + tx * 4) = o;
    }
    lpart[((size_t)split * Hn + h) * Qn + qp] = lacc0 + lacc1;
}

// K4: rl[q][h] = 1 / sum over splits of lpart
__global__ __launch_bounds__(256) void lcomb_kernel(const float* __restrict__ lpart,
                                                    float* __restrict__ rl) {
    int idx = blockIdx.x * 256 + threadIdx.x;   // 32768
    int q = idx >> 3, h = idx & 7;
    float l = 0.f;
#pragma unroll
    for (int s2 = 0; s2 < 4; ++s2)
        l += lpart[((size_t)s2 * Hn + h) * Qn + q];
    rl[idx] = 1.0f / l;
}

// ---------------------------------------------------------------------------
extern "C" void kernel_launch(void* const* d_in, const int* in_sizes, int n_in,
                              void* d_out, int out_size, void* d_ws, size_t ws_size,
                              hipStream_t stream) {
    const float* qpos   = (const float*)d_in[0];
    const float* q      = (const float*)d_in[1];
    // d_in[2] = k (unused by the reference)
    const float* v      = (const float*)d_in[3];
    const void*  mask   = d_in[4];               // bool mask; layout probed on-device
    const float* W_tau  = (const float*)d_in[5];
    const float* b_tau  = (const float*)d_in[6];
    const float* ln_v_g = (const float*)d_in[7];
    const float* ln_v_b = (const float*)d_in[8];
    const float* W_v    = (const float*)d_in[9];
    const float* b_v    = (const float*)d_in[10];
    const float* W_proj = (const float*)d_in[11];
    const float* b_proj = (const float*)d_in[12];
    const float* ln_pre_g = (const float*)d_in[13];
    const float* ln_pre_b = (const float*)d_in[14];
    const float* W_m1   = (const float*)d_in[15];
    const float* b_m1   = (const float*)d_in[16];
    const float* W_m2   = (const float*)d_in[17];
    const float* b_m2   = (const float*)d_in[18];
    const float* ln_post_g = (const float*)d_in[19];
    const float* ln_post_b = (const float*)d_in[20];
    float* out = (float*)d_out;
    float* ws = (float*)d_ws;

    // ws layout (floats), total 9,150,464 floats ~= 36.6 MB.
    // mb_b is 4096 x 64 u64 = 2MB = 524288 floats (R7 fix: was 131072).
    // hmid/hraw reuse dead regions (vln+vp dead after pv; apart dead after proj).
    float* tau_b   = ws + 0;          // 32768
    float* ctr_b   = ws + 32768;      // 8192
    float* m_b     = ws + 40960;      // 32768
    float* rl_b    = ws + 73728;      // 32768
    float* lp_b    = ws + 106496;     // 131072  (4 splits x H x Q)
    unsigned long long* mb_b = (unsigned long long*)(ws + 237568);  // 524288 floats = 2MB
    float* vln_b   = ws + 761856;     // 1048576
    float* vp_b    = ws + 1810432;    // 1048576
    float* ap_b    = ws + 2859008;    // 4 x 1048576
    float* zraw_b  = ws + 7053312;    // 1048576
    float* zpre_b  = ws + 8101888;    // 1048576
    float* hmid_b  = ws + 761856;     // reuse vln+vp (dead after pv)   2097152
    float* hraw_b  = ws + 2859008;    // reuse apart (dead after proj)  1048576

    prep_kernel<<<Qn * Hn / 256, 256, 0, stream>>>(qpos, q, W_tau, b_tau, tau_b, ctr_b);
    dminmax_kernel<<<Qn / 4, 256, 0, stream>>>(mask, ctr_b, tau_b, mb_b, m_b);
    ln_kernel<<<Qn, 64, 0, stream>>>(v, nullptr, ln_v_g, ln_v_b, vln_b);
    gemm_kernel<0, 1, 0><<<dim3(Qn / 64, Cn / 64), 256, 0, stream>>>(vln_b, W_v, b_v, nullptr, vp_b, Qn, Cn, Cn);
    pv_kernel<<<dim3(Qn / 256, Hn, 4), 256, 0, stream>>>(ctr_b, tau_b, (const unsigned*)mb_b, vp_b, m_b, ap_b, lp_b);
    lcomb_kernel<<<Qn * Hn / 256, 256, 0, stream>>>(lp_b, rl_b);
    gemm_kernel<0, 4, 1><<<dim3(Qn / 64, Cn / 64), 256, 0, stream>>>(ap_b, W_proj, b_proj, rl_b, zraw_b, Qn, Cn, Cn);
    ln_kernel<<<Qn, 64, 0, stream>>>(zraw_b, nullptr, ln_pre_g, ln_pre_b, zpre_b);
    gemm_kernel<1, 1, 0><<<dim3(Qn / 64, 2 * Cn / 64), 256, 0, stream>>>(zpre_b, W_m1, b_m1, nullptr, hmid_b, Qn, 2 * Cn, Cn);
    gemm_kernel<0, 1, 0><<<dim3(Qn / 64, Cn / 64), 256, 0, stream>>>(hmid_b, W_m2, b_m2, nullptr, hraw_b, Qn, Cn, 2 * Cn);
    ln_kernel<<<Qn, 64, 0, stream>>>(zpre_b, hraw_b, ln_post_g, ln_post_b, out);
}